// Round 3
// baseline (192.665 us; speedup 1.0000x reference)
//
#include <hip/hip_runtime.h>
#include <cstddef>

// SystemIDModel: y[k] = poly8(x2[k]) - x1[k] - R0*u[k]
//   x1[k] = A00*x1[k-1] + B0*u[k-1]   (x1[0]=0)   A00 = exp(-dt/(Rp*Cp)), B0 = Rp*(1-A00)
//   x2[k] = x2[k-1] + B1*u[k-1]       (x2[0]=1)   B1 = -1/5400
// Single-dispatch decoupled-lookback scan, fp64 internally.
// Cross-block carries:
//   P (plain prefix sum, for x2): full segmented lookback, combine = add.
//   W (weighted sum, for x1): W_b = dC*W_{b-1} + aggW[b-1], dC = A00^CHUNK.
//     For this benchmark dC = exp(-4096) underflows to exactly 0.0, so the
//     carry is just the immediate predecessor's aggregate (inclW==aggW when
//     dC==0) — NO waiting on its inclusive. General dC>0 serial path kept.

constexpr int BLOCK = 256;
constexpr int TPER  = 16;
constexpr int CHUNK = BLOCK * TPER;   // 4096
constexpr int NTOT  = 4194304;
constexpr int NB    = NTOT / CHUNK;   // 1024

struct ScanWS {
    int    flags[NB];    // 0 = empty, 1 = aggregate ready, 2 = inclusive ready
    int    ticket;       // dynamic block-id counter
    int    _pad[15];
    double aggP[NB];
    double aggW[NB];
    double inclP[NB];
    double inclW[NB];
};

__device__ inline void store_d(double* p, double v) {
    __hip_atomic_store((unsigned long long*)p,
                       __builtin_bit_cast(unsigned long long, v),
                       __ATOMIC_RELAXED, __HIP_MEMORY_SCOPE_AGENT);
}
__device__ inline double load_d(const double* p) {
    unsigned long long x = __hip_atomic_load((const unsigned long long*)p,
                                             __ATOMIC_RELAXED, __HIP_MEMORY_SCOPE_AGENT);
    return __builtin_bit_cast(double, x);
}

__global__ __launch_bounds__(BLOCK) void fused_scan(
    const float* __restrict__ u,
    const float* __restrict__ Rp_p, const float* __restrict__ Cp_p,
    const float* __restrict__ R0_p, const float* __restrict__ ac,
    ScanWS* __restrict__ ws,
    float* __restrict__ out)
{
    __shared__ double sS[2][BLOCK];
    __shared__ double sP[2][BLOCK];
    __shared__ int    s_bid;
    __shared__ double s_cP, s_cW;

    const int t = threadIdx.x;
    if (t == 0)
        s_bid = __hip_atomic_fetch_add(&ws->ticket, 1, __ATOMIC_RELAXED,
                                       __HIP_MEMORY_SCOPE_AGENT);

    const double Rp    = (double)Rp_p[0], Cp = (double)Cp_p[0];
    const double invRC = 1.0 / (Rp * Cp);
    const double A00   = exp(-invRC);
    const double B0    = Rp * (1.0 - A00);
    const double B1    = -1.0 / 5400.0;                // -eta*dt/(1.5*3600)
    const double R0    = (double)R0_p[0];
    const double dC    = exp(-(double)CHUNK * invRC);  // exactly 0.0 for Rp*Cp=1

    __syncthreads();
    const int bid = s_bid;

    // ---- load 16 contiguous floats per thread ----
    const size_t base = (size_t)bid * CHUNK + (size_t)t * TPER;
    const float4* up = (const float4*)(u + base);
    float4 v[4];
    v[0] = up[0]; v[1] = up[1]; v[2] = up[2]; v[3] = up[3];
    const float* uu = (const float*)v;

    // ---- thread-local aggregates ----
    double s = 0.0, p = 0.0;
#pragma unroll
    for (int i = 0; i < TPER; ++i) { s = A00 * s + (double)uu[i]; p += (double)uu[i]; }
    sS[0][t] = s; sP[0][t] = p;
    __syncthreads();

    // ---- block-level inclusive Hillis-Steele scan (W weighted, P plain) ----
    double f = exp(-(double)TPER * invRC);   // A00^TPER
    int cur = 0;
    for (int d = 1; d < BLOCK; d <<= 1) {
        const int nxt = cur ^ 1;
        double w = sS[cur][t], q = sP[cur][t];
        if (t >= d) { w = sS[cur][t - d] * f + w; q = sP[cur][t - d] + q; }
        sS[nxt][t] = w; sP[nxt][t] = q;
        cur = nxt; f *= f;
        __syncthreads();
    }
    const double exW  = t ? sS[cur][t - 1] : 0.0;
    const double exP  = t ? sP[cur][t - 1] : 0.0;
    const double totW = sS[cur][BLOCK - 1];
    const double totP = sP[cur][BLOCK - 1];

    // ---- publish ----
    if (t == 0) {
        if (bid == 0) {
            store_d(&ws->inclP[0], totP);
            store_d(&ws->inclW[0], totW);   // cW=0: inclW = 0*dC + totW
            __hip_atomic_store(&ws->flags[0], 2, __ATOMIC_RELEASE,
                               __HIP_MEMORY_SCOPE_AGENT);
            s_cP = 0.0; s_cW = 0.0;
        } else {
            store_d(&ws->aggP[bid], totP);
            store_d(&ws->aggW[bid], totW);
            __hip_atomic_store(&ws->flags[bid], 1, __ATOMIC_RELEASE,
                               __HIP_MEMORY_SCOPE_AGENT);
        }
    }

    // ---- wave-parallel decoupled lookback (wave 0 only) ----
    if (bid > 0 && t < 64) {
        double carry = 0.0;
        int end = bid;                       // predecessors [0, end) unresolved
        for (;;) {
            const int idx = end - 64 + t;
            int fl = 0;
            if (idx >= 0) {
                fl = __hip_atomic_load(&ws->flags[idx], __ATOMIC_ACQUIRE,
                                       __HIP_MEMORY_SCOPE_AGENT);
                while (fl == 0) {
                    __builtin_amdgcn_s_sleep(1);
                    fl = __hip_atomic_load(&ws->flags[idx], __ATOMIC_ACQUIRE,
                                           __HIP_MEMORY_SCOPE_AGENT);
                }
            }
            const unsigned long long incl = __ballot(fl == 2);
            const int hl = incl ? (63 - __builtin_clzll(incl)) : 0;
            double val = 0.0;
            if (idx >= 0 && (!incl || t >= hl))
                val = (incl && t == hl) ? load_d(&ws->inclP[idx])
                                        : load_d(&ws->aggP[idx]);
            for (int off = 32; off; off >>= 1) val += __shfl_down(val, off, 64);
            carry += val;                    // lane 0 holds the wave sum
            if (incl) break;
            end -= 64;
            if (end <= 0) break;             // unreachable: block 0 posts flag=2
        }
        if (t == 0) {
            // Weighted carry: W_bid = dC*W_{bid-1} + aggW[bid-1].
            double cW;
            if (dC == 0.0) {
                // inclW[b-1] == aggW[b-1] numerically; flag already != 0
                // (lane 63 of the first window waited on flags[bid-1]).
                int fl1 = __hip_atomic_load(&ws->flags[bid - 1], __ATOMIC_ACQUIRE,
                                            __HIP_MEMORY_SCOPE_AGENT);
                while (fl1 == 0) {
                    __builtin_amdgcn_s_sleep(1);
                    fl1 = __hip_atomic_load(&ws->flags[bid - 1], __ATOMIC_ACQUIRE,
                                            __HIP_MEMORY_SCOPE_AGENT);
                }
                cW = (fl1 == 2) ? load_d(&ws->inclW[bid - 1])
                                : load_d(&ws->aggW[bid - 1]);
            } else {
                // general serial chain (never taken for this benchmark)
                int fl1;
                do {
                    fl1 = __hip_atomic_load(&ws->flags[bid - 1], __ATOMIC_ACQUIRE,
                                            __HIP_MEMORY_SCOPE_AGENT);
                    if (fl1 != 2) __builtin_amdgcn_s_sleep(1);
                } while (fl1 != 2);
                cW = load_d(&ws->inclW[bid - 1]);
            }
            s_cP = carry; s_cW = cW;
            store_d(&ws->inclP[bid], carry + totP);
            store_d(&ws->inclW[bid], cW * dC + totW);
            __hip_atomic_store(&ws->flags[bid], 2, __ATOMIC_RELEASE,
                               __HIP_MEMORY_SCOPE_AGENT);
        }
    }
    __syncthreads();
    const double cP = s_cP, cWb = s_cW;

    // ---- emit 16 outputs per thread ----
    double a[9];
#pragma unroll
    for (int i = 0; i < 9; ++i) a[i] = (double)ac[i];

    double Wcur = cWb * exp(-(double)(TPER * t) * invRC) + exW;  // W at element base
    double Pcur = cP + exP;

    float4 o[4];
    float* oy = (float*)o;
#pragma unroll
    for (int i = 0; i < TPER; ++i) {
        const double x2 = 1.0 + B1 * Pcur;   // INITIAL_X2 = 1
        double poly = a[8];
#pragma unroll
        for (int j = 7; j >= 0; --j) poly = poly * x2 + a[j];
        oy[i] = (float)(poly - B0 * Wcur - R0 * (double)uu[i]);
        Wcur = A00 * Wcur + (double)uu[i];   // emit state BEFORE update
        Pcur += (double)uu[i];
    }
    float4* op = (float4*)(out + base);
    op[0] = o[0]; op[1] = o[1]; op[2] = o[2]; op[3] = o[3];
}

extern "C" void kernel_launch(void* const* d_in, const int* in_sizes, int n_in,
                              void* d_out, int out_size, void* d_ws, size_t ws_size,
                              hipStream_t stream) {
    const float* u    = (const float*)d_in[0];
    const float* Rp_p = (const float*)d_in[1];
    const float* Cp_p = (const float*)d_in[2];
    const float* R0_p = (const float*)d_in[3];
    const float* ac   = (const float*)d_in[4];
    float* out = (float*)d_out;
    ScanWS* ws = (ScanWS*)d_ws;

    // flags + ticket are poisoned to 0xAA before every launch — zero them.
    hipMemsetAsync(d_ws, 0, offsetof(ScanWS, aggP), stream);
    fused_scan<<<NB, BLOCK, 0, stream>>>(u, Rp_p, Cp_p, R0_p, ac, ws, out);
}

// Round 4
// 87.501 us; speedup vs baseline: 2.2019x; 2.2019x over previous
//
#include <hip/hip_runtime.h>

// SystemIDModel: y[k] = poly8(x2[k]) - x1[k] - R0*u[k]
//   x1[k] = A00*x1[k-1] + B0*u[k-1]   (x1[0]=0)   A00 = exp(-dt/(Rp*Cp)), B0 = Rp*(1-A00)
//   x2[k] = x2[k-1] + B1*u[k-1]       (x2[0]=1)   B1 = -1/5400
//
// Two deterministic dispatches, fp64 internally, NO inter-block sync:
//   kA: per-chunk aggregates (weighted sum W, plain sum P)       [read u]
//   kB: each block redundantly reduces its own carry from the 16 KB aggregate
//       array (L2-resident), rescans its chunk, emits.           [read u, write y]
// Cross-chunk W carry decays by dC = A00^CHUNK = exp(-2048/RpCp) -> exactly 0.0
// for this benchmark, so carryW = aggW[b-1]; serial fallback kept for dC>0.

constexpr int BLOCK = 256;
constexpr int TPER  = 8;
constexpr int CHUNK = BLOCK * TPER;    // 2048
constexpr int NTOT  = 4194304;
constexpr int NB    = NTOT / CHUNK;    // 2048
constexpr int APT   = NB / BLOCK;      // aggregates per thread in kB = 8

// ---------------- Kernel A: per-chunk aggregates ----------------
__global__ __launch_bounds__(BLOCK) void kA_agg(
    const float* __restrict__ u,
    const float* __restrict__ Rp_p, const float* __restrict__ Cp_p,
    double* __restrict__ aggW, double* __restrict__ aggP)
{
    __shared__ double sW[BLOCK];
    __shared__ double sP[BLOCK];
    const int b = blockIdx.x, t = threadIdx.x;
    const double invRC = 1.0 / ((double)Rp_p[0] * (double)Cp_p[0]);
    const double A00   = exp(-invRC);

    const float4* up = (const float4*)(u + (size_t)b * CHUNK + (size_t)t * TPER);
    float4 v[2];
    v[0] = up[0]; v[1] = up[1];
    const float* uu = (const float*)v;

    double s = 0.0, p = 0.0;
#pragma unroll
    for (int i = 0; i < TPER; ++i) { s = A00 * s + (double)uu[i]; p += (double)uu[i]; }
    sW[t] = s; sP[t] = p;
    __syncthreads();

    // ordered tree reduce: combine(L,R): W = W_L * A00^{len_R} + W_R
    double f = exp(-(double)TPER * invRC);   // A00^TPER
    for (int stride = 1; stride < BLOCK; stride <<= 1) {
        if ((t & (2 * stride - 1)) == 0) {
            sW[t] = sW[t] * f + sW[t + stride];
            sP[t] = sP[t] + sP[t + stride];
        }
        f *= f;
        __syncthreads();
    }
    if (t == 0) { aggW[b] = sW[0]; aggP[b] = sP[0]; }
}

// ---------------- Kernel B: carry reduce + rescan + emit ----------------
__global__ __launch_bounds__(BLOCK) void kB_emit(
    const float* __restrict__ u,
    const float* __restrict__ Rp_p, const float* __restrict__ Cp_p,
    const float* __restrict__ R0_p, const float* __restrict__ ac,
    const double* __restrict__ aggW, const double* __restrict__ aggP,
    float* __restrict__ out)
{
    __shared__ double sS[2][BLOCK];
    __shared__ double sP[2][BLOCK];
    __shared__ double sRed[BLOCK / 64];
    __shared__ double sCW;

    const int b = blockIdx.x, t = threadIdx.x;
    const double Rp    = (double)Rp_p[0], Cp = (double)Cp_p[0];
    const double invRC = 1.0 / (Rp * Cp);
    const double A00   = exp(-invRC);
    const double B0    = Rp * (1.0 - A00);
    const double B1    = -1.0 / 5400.0;               // -eta*dt/(1.5*3600)
    const double R0    = (double)R0_p[0];
    const double dC    = exp(-(double)CHUNK * invRC); // exactly 0.0 here

    // ---- load this thread's 8 u values ----
    const size_t base = (size_t)b * CHUNK + (size_t)t * TPER;
    const float4* up = (const float4*)(u + base);
    float4 v[2];
    v[0] = up[0]; v[1] = up[1];
    const float* uu = (const float*)v;

    // ---- carryP: block-parallel masked reduce of aggP[0..b) ----
    double pc = 0.0;
#pragma unroll
    for (int i = 0; i < APT; ++i) {
        const int j = t * APT + i;
        if (j < b) pc += aggP[j];
    }
    for (int off = 32; off; off >>= 1) pc += __shfl_down(pc, off, 64);
    if ((t & 63) == 0) sRed[t >> 6] = pc;

    // ---- carryW ----
    if (t == 0) {
        double cW;
        if (dC == 0.0) {
            cW = (b > 0) ? aggW[b - 1] : 0.0;
        } else {                                  // general serial fallback
            cW = 0.0;
            for (int j = 0; j < b; ++j) cW = cW * dC + aggW[j];
        }
        sCW = cW;
    }

    // ---- thread-local aggregates ----
    double s = 0.0, p = 0.0;
#pragma unroll
    for (int i = 0; i < TPER; ++i) { s = A00 * s + (double)uu[i]; p += (double)uu[i]; }
    sS[0][t] = s; sP[0][t] = p;
    __syncthreads();

    double carryP = 0.0;
#pragma unroll
    for (int w = 0; w < BLOCK / 64; ++w) carryP += sRed[w];
    const double carryW = sCW;

    // ---- block-level inclusive Hillis-Steele scan ----
    double f = exp(-(double)TPER * invRC);   // A00^TPER
    int cur = 0;
    for (int d = 1; d < BLOCK; d <<= 1) {
        const int nxt = cur ^ 1;
        double w = sS[cur][t], q = sP[cur][t];
        if (t >= d) { w = sS[cur][t - d] * f + w; q = sP[cur][t - d] + q; }
        sS[nxt][t] = w; sP[nxt][t] = q;
        cur = nxt; f *= f;
        __syncthreads();
    }
    const double exW = t ? sS[cur][t - 1] : 0.0;
    const double exP = t ? sP[cur][t - 1] : 0.0;

    // ---- emit 8 outputs per thread ----
    double a[9];
#pragma unroll
    for (int i = 0; i < 9; ++i) a[i] = (double)ac[i];

    double Wcur = carryW * exp(-(double)(TPER * t) * invRC) + exW;  // W at elem base
    double Pcur = carryP + exP;

    float4 o[2];
    float* oy = (float*)o;
#pragma unroll
    for (int i = 0; i < TPER; ++i) {
        const double x2 = 1.0 + B1 * Pcur;   // INITIAL_X2 = 1
        double poly = a[8];
#pragma unroll
        for (int j = 7; j >= 0; --j) poly = poly * x2 + a[j];
        oy[i] = (float)(poly - B0 * Wcur - R0 * (double)uu[i]);
        Wcur = A00 * Wcur + (double)uu[i];   // emit state BEFORE update
        Pcur += (double)uu[i];
    }
    float4* op = (float4*)(out + base);
    op[0] = o[0]; op[1] = o[1];
}

extern "C" void kernel_launch(void* const* d_in, const int* in_sizes, int n_in,
                              void* d_out, int out_size, void* d_ws, size_t ws_size,
                              hipStream_t stream) {
    const float* u    = (const float*)d_in[0];
    const float* Rp_p = (const float*)d_in[1];
    const float* Cp_p = (const float*)d_in[2];
    const float* R0_p = (const float*)d_in[3];
    const float* ac   = (const float*)d_in[4];
    float* out = (float*)d_out;

    double* wsW = (double*)d_ws;        // [NB]
    double* wsP = (double*)d_ws + NB;   // [NB]

    kA_agg <<<NB, BLOCK, 0, stream>>>(u, Rp_p, Cp_p, wsW, wsP);
    kB_emit<<<NB, BLOCK, 0, stream>>>(u, Rp_p, Cp_p, R0_p, ac, wsW, wsP, out);
}

// Round 6
// 85.166 us; speedup vs baseline: 2.2622x; 1.0274x over previous
//
#include <hip/hip_runtime.h>

// SystemIDModel: y[k] = poly8(x2[k]) - x1[k] - R0*u[k]
//   x1[k] = A00*x1[k-1] + B0*u[k-1]   (x1[0]=0)   A00 = exp(-dt/(Rp*Cp)), B0 = Rp*(1-A00)
//   x2[k] = x2[k-1] + B1*u[k-1]       (x2[0]=1)   B1 = -1/5400
//
// Deterministic 2-dispatch chunked scan (no inter-block sync, no cooperative):
//   kA: per-chunk aggregates (weighted W, plain P) — wave shuffle scan, 1 barrier
//   kB: redundant carry reduce + wave shuffle scan + emit — 1 barrier
// All decay powers via repeated squaring (single exp() libcall per thread).
// fp64 for scan chains (P needs it); fp32 for the poly epilogue.
// Cross-chunk W carry: W_b = dC*W_{b-1} + aggW[b-1]; dC = A00^CHUNK underflows
// to exactly 0.0 for this benchmark (Rp=Cp=1) -> carryW = aggW[b-1];
// general dC>0 serial fallback kept (never taken here).

constexpr int BLOCK = 256;
constexpr int TPER  = 16;
constexpr int CHUNK = BLOCK * TPER;    // 4096
constexpr int NTOT  = 4194304;
constexpr int NB    = NTOT / CHUNK;    // 1024
constexpr int WPB   = BLOCK / 64;      // 4 waves per block
constexpr int APT   = NB / BLOCK;      // aggP entries per thread in kB = 4

// ---------------- Kernel A: per-chunk aggregates ----------------
__global__ __launch_bounds__(BLOCK) void kA_agg(
    const float* __restrict__ u,
    const float* __restrict__ Rp_p, const float* __restrict__ Cp_p,
    double* __restrict__ aggW, double* __restrict__ aggP)
{
    __shared__ double LW[WPB], LP[WPB];
    const int b = blockIdx.x, t = threadIdx.x;
    const int lane = t & 63, w = t >> 6;

    const double invRC = 1.0 / ((double)Rp_p[0] * (double)Cp_p[0]);
    const double A00 = exp(-invRC);
    const double a2 = A00 * A00, a4 = a2 * a2, a8 = a4 * a4;
    const double f16 = a8 * a8;                         // A00^TPER

    const float4* up = (const float4*)(u + (size_t)b * CHUNK + (size_t)t * TPER);
    float4 v[4];
    v[0] = up[0]; v[1] = up[1]; v[2] = up[2]; v[3] = up[3];
    const float* uu = (const float*)v;

    double s = 0.0, p = 0.0;
#pragma unroll
    for (int i = 0; i < TPER; ++i) { s = A00 * s + (double)uu[i]; p += (double)uu[i]; }

    // wave-level inclusive scan (weighted W, plain P), 6 shuffle rounds
    double fk = f16;
#pragma unroll
    for (int k = 1; k < 64; k <<= 1) {
        const double sw = __shfl_up(s, k, 64);
        const double pw = __shfl_up(p, k, 64);
        if (lane >= k) { s = sw * fk + s; p += pw; }
        fk *= fk;
    }
    if (lane == 63) { LW[w] = s; LP[w] = p; }
    __syncthreads();

    if (t == 0) {
        double f1024 = f16;                              // A00^(16*64)
        for (int i = 0; i < 6; ++i) f1024 *= f1024;      // underflows to 0.0 here
        double W = LW[0], P = LP[0];
        for (int v2 = 1; v2 < WPB; ++v2) { W = W * f1024 + LW[v2]; P += LP[v2]; }
        aggW[b] = W; aggP[b] = P;
    }
}

// ---------------- Kernel B: carry reduce + rescan + emit ----------------
__global__ __launch_bounds__(BLOCK) void kB_emit(
    const float* __restrict__ u,
    const float* __restrict__ Rp_p, const float* __restrict__ Cp_p,
    const float* __restrict__ R0_p, const float* __restrict__ ac,
    const double* __restrict__ aggW, const double* __restrict__ aggP,
    float* __restrict__ out)
{
    __shared__ double LW[WPB], LP[WPB];
    __shared__ double sRed[WPB];
    __shared__ double sCW;

    const int b = blockIdx.x, t = threadIdx.x;
    const int lane = t & 63, w = t >> 6;

    const double invRC = 1.0 / ((double)Rp_p[0] * (double)Cp_p[0]);
    const double A00 = exp(-invRC);
    const double B0  = (double)Rp_p[0] * (1.0 - A00);
    const double B1  = -1.0 / 5400.0;                    // -eta*dt/(1.5*3600)
    const float  R0f = R0_p[0];
    const double a2 = A00 * A00, a4 = a2 * a2, a8 = a4 * a4;
    const double f16 = a8 * a8;                          // A00^TPER
    double f1024 = f16;
    for (int i = 0; i < 6; ++i) f1024 *= f1024;          // A00^1024 (0.0 here)
    const double dC = (f1024 * f1024) * (f1024 * f1024); // A00^CHUNK (0.0 here)

    // ---- own chunk loads ----
    const size_t base = (size_t)b * CHUNK + (size_t)t * TPER;
    const float4* up = (const float4*)(u + base);
    float4 v[4];
    v[0] = up[0]; v[1] = up[1]; v[2] = up[2]; v[3] = up[3];
    const float* uu = (const float*)v;

    // ---- carryP partial: block-parallel masked reduce of aggP[0..b) ----
    double pc = 0.0;
#pragma unroll
    for (int i = 0; i < APT; ++i) {
        const int j = t * APT + i;
        if (j < b) pc += aggP[j];
    }
#pragma unroll
    for (int off = 32; off; off >>= 1) pc += __shfl_down(pc, off, 64);
    if (lane == 0) sRed[w] = pc;

    // ---- carryW (block) ----
    if (t == 0) {
        double cW;
        if (dC == 0.0) {
            cW = (b > 0) ? aggW[b - 1] : 0.0;
        } else {                                         // general fallback
            cW = 0.0;
            for (int j = 0; j < b; ++j) cW = cW * dC + aggW[j];
        }
        sCW = cW;
    }

    // ---- thread aggregates + wave shuffle scan ----
    double s = 0.0, p = 0.0;
#pragma unroll
    for (int i = 0; i < TPER; ++i) { s = A00 * s + (double)uu[i]; p += (double)uu[i]; }
    double fk = f16;
#pragma unroll
    for (int k = 1; k < 64; k <<= 1) {
        const double sw = __shfl_up(s, k, 64);
        const double pw = __shfl_up(p, k, 64);
        if (lane >= k) { s = sw * fk + s; p += pw; }
        fk *= fk;
    }
    if (lane == 63) { LW[w] = s; LP[w] = p; }
    __syncthreads();                                     // the ONLY barrier

    // ---- assemble per-thread exclusive prefixes ----
    double carryP_blk = 0.0;
#pragma unroll
    for (int v2 = 0; v2 < WPB; ++v2) carryP_blk += sRed[v2];

    double cw = 0.0, cp = 0.0;                           // previous-wave carries
    for (int v2 = 0; v2 < w; ++v2) { cw = cw * f1024 + LW[v2]; cp += LP[v2]; }

    double fw = 1.0;                                     // f1024^w
    for (int v2 = 0; v2 < w; ++v2) fw *= f1024;

    double fl = 1.0, bse = f16;                          // f16^lane (square-multiply)
#pragma unroll
    for (int k = 0; k < 6; ++k) { if (lane & (1 << k)) fl *= bse; bse *= bse; }

    const double upW = __shfl_up(s, 1, 64);
    const double upP = __shfl_up(p, 1, 64);
    double Wcur = (lane ? upW : 0.0) + (cw + sCW * fw) * fl;   // W at elem base
    double Pcur = (lane ? upP : 0.0) + cp + carryP_blk;        // P at elem base

    // ---- emit 16 outputs/thread: fp32 poly, fp64 state chains ----
    float af[9];
#pragma unroll
    for (int i = 0; i < 9; ++i) af[i] = ac[i];

    float4 o[4];
    float* oy = (float*)o;
#pragma unroll
    for (int i = 0; i < TPER; ++i) {
        const float x2 = (float)(1.0 + B1 * Pcur);       // INITIAL_X2 = 1
        float poly = af[8];
#pragma unroll
        for (int j = 7; j >= 0; --j) poly = fmaf(poly, x2, af[j]);
        oy[i] = poly - (float)(B0 * Wcur) - R0f * uu[i];
        Wcur = A00 * Wcur + (double)uu[i];               // emit state BEFORE update
        Pcur += (double)uu[i];
    }
    float4* op = (float4*)(out + base);
    op[0] = o[0]; op[1] = o[1]; op[2] = o[2]; op[3] = o[3];
}

extern "C" void kernel_launch(void* const* d_in, const int* in_sizes, int n_in,
                              void* d_out, int out_size, void* d_ws, size_t ws_size,
                              hipStream_t stream) {
    const float* u    = (const float*)d_in[0];
    const float* Rp_p = (const float*)d_in[1];
    const float* Cp_p = (const float*)d_in[2];
    const float* R0_p = (const float*)d_in[3];
    const float* ac   = (const float*)d_in[4];
    float* out = (float*)d_out;

    double* wsW = (double*)d_ws;        // [NB]
    double* wsP = (double*)d_ws + NB;   // [NB]

    kA_agg <<<NB, BLOCK, 0, stream>>>(u, Rp_p, Cp_p, wsW, wsP);
    kB_emit<<<NB, BLOCK, 0, stream>>>(u, Rp_p, Cp_p, R0_p, ac, wsW, wsP, out);
}

// Round 7
// 84.614 us; speedup vs baseline: 2.2770x; 1.0065x over previous
//
#include <hip/hip_runtime.h>

// SystemIDModel: y[k] = poly8(x2[k]) - x1[k] - R0*u[k]
//   x1[k] = A00*x1[k-1] + B0*u[k-1]   (x1[0]=0)   A00 = exp(-dt/(Rp*Cp)), B0 = Rp*(1-A00)
//   x2[k] = x2[k-1] + B1*u[k-1]       (x2[0]=1)   B1 = -1/5400
//
// Deterministic 2-dispatch chunked scan, ALL-FP32 (error analysis: tree-structured
// fp32 prefix sums of 4M normals give x2 error ~5e-7 vs threshold 7.25e-2).
//   kA: per-chunk aggregates (weighted W, plain P) — wave shuffle scan, 1 barrier
//   kB: redundant carry reduce + wave shuffle scan + emit — 1 barrier
// Decay powers via repeated squaring (one expf per thread).
// Cross-chunk W carry: W_b = dC*W_{b-1} + aggW[b-1]; dC = A00^CHUNK underflows to
// exactly 0.0f here (Rp=Cp=1) -> carryW = aggW[b-1]; general fallback retained.

constexpr int BLOCK = 256;
constexpr int TPER  = 16;
constexpr int CHUNK = BLOCK * TPER;    // 4096
constexpr int NTOT  = 4194304;
constexpr int NB    = NTOT / CHUNK;    // 1024
constexpr int WPB   = BLOCK / 64;      // 4 waves per block
constexpr int APT   = NB / BLOCK;      // aggP entries per thread in kB = 4

// ---------------- Kernel A: per-chunk aggregates ----------------
__global__ __launch_bounds__(BLOCK) void kA_agg(
    const float* __restrict__ u,
    const float* __restrict__ Rp_p, const float* __restrict__ Cp_p,
    float* __restrict__ aggW, float* __restrict__ aggP)
{
    __shared__ float LW[WPB], LP[WPB];
    const int b = blockIdx.x, t = threadIdx.x;
    const int lane = t & 63, w = t >> 6;

    const float invRC = 1.0f / (Rp_p[0] * Cp_p[0]);
    const float A00 = __expf(-invRC);
    const float a2 = A00 * A00, a4 = a2 * a2, a8 = a4 * a4;
    const float f16 = a8 * a8;                          // A00^TPER

    const float4* up = (const float4*)(u + (size_t)b * CHUNK + (size_t)t * TPER);
    float4 v[4];
    v[0] = up[0]; v[1] = up[1]; v[2] = up[2]; v[3] = up[3];
    const float* uu = (const float*)v;

    float s = 0.0f, p = 0.0f;
#pragma unroll
    for (int i = 0; i < TPER; ++i) { s = fmaf(A00, s, uu[i]); p += uu[i]; }

    // wave-level inclusive scan (weighted W, plain P), 6 shuffle rounds
    float fk = f16;
#pragma unroll
    for (int k = 1; k < 64; k <<= 1) {
        const float sw = __shfl_up(s, k, 64);
        const float pw = __shfl_up(p, k, 64);
        if (lane >= k) { s = fmaf(sw, fk, s); p += pw; }
        fk *= fk;
    }
    if (lane == 63) { LW[w] = s; LP[w] = p; }
    __syncthreads();

    if (t == 0) {
        float f1024 = f16;                               // A00^(16*64)
        for (int i = 0; i < 6; ++i) f1024 *= f1024;      // 0.0f here (underflow)
        float W = LW[0], P = LP[0];
        for (int q = 1; q < WPB; ++q) { W = fmaf(W, f1024, LW[q]); P += LP[q]; }
        aggW[b] = W; aggP[b] = P;
    }
}

// ---------------- Kernel B: carry reduce + rescan + emit ----------------
__global__ __launch_bounds__(BLOCK) void kB_emit(
    const float* __restrict__ u,
    const float* __restrict__ Rp_p, const float* __restrict__ Cp_p,
    const float* __restrict__ R0_p, const float* __restrict__ ac,
    const float* __restrict__ aggW, const float* __restrict__ aggP,
    float* __restrict__ out)
{
    __shared__ float LW[WPB], LP[WPB];
    __shared__ float sRed[WPB];
    __shared__ float sCW;

    const int b = blockIdx.x, t = threadIdx.x;
    const int lane = t & 63, w = t >> 6;

    const float invRC = 1.0f / (Rp_p[0] * Cp_p[0]);
    const float A00 = __expf(-invRC);
    const float B0  = Rp_p[0] * (1.0f - A00);
    const float B1  = -1.0f / 5400.0f;                   // -eta*dt/(1.5*3600)
    const float R0f = R0_p[0];
    const float a2 = A00 * A00, a4 = a2 * a2, a8 = a4 * a4;
    const float f16 = a8 * a8;                           // A00^TPER
    float f1024 = f16;
    for (int i = 0; i < 6; ++i) f1024 *= f1024;          // A00^1024 (0.0f here)
    const float dC = (f1024 * f1024) * (f1024 * f1024);  // A00^CHUNK (0.0f here)

    // ---- own chunk loads ----
    const size_t base = (size_t)b * CHUNK + (size_t)t * TPER;
    const float4* up = (const float4*)(u + base);
    float4 v[4];
    v[0] = up[0]; v[1] = up[1]; v[2] = up[2]; v[3] = up[3];
    const float* uu = (const float*)v;

    // ---- carryP partial: block-parallel masked reduce of aggP[0..b) ----
    float pc = 0.0f;
#pragma unroll
    for (int i = 0; i < APT; ++i) {
        const int j = t * APT + i;
        if (j < b) pc += aggP[j];
    }
#pragma unroll
    for (int off = 32; off; off >>= 1) pc += __shfl_down(pc, off, 64);
    if (lane == 0) sRed[w] = pc;

    // ---- carryW (block) ----
    if (t == 0) {
        float cW;
        if (dC == 0.0f) {
            cW = (b > 0) ? aggW[b - 1] : 0.0f;
        } else {                                         // general fallback
            cW = 0.0f;
            for (int j = 0; j < b; ++j) cW = fmaf(cW, dC, aggW[j]);
        }
        sCW = cW;
    }

    // ---- thread aggregates + wave shuffle scan ----
    float s = 0.0f, p = 0.0f;
#pragma unroll
    for (int i = 0; i < TPER; ++i) { s = fmaf(A00, s, uu[i]); p += uu[i]; }
    float fk = f16;
#pragma unroll
    for (int k = 1; k < 64; k <<= 1) {
        const float sw = __shfl_up(s, k, 64);
        const float pw = __shfl_up(p, k, 64);
        if (lane >= k) { s = fmaf(sw, fk, s); p += pw; }
        fk *= fk;
    }
    if (lane == 63) { LW[w] = s; LP[w] = p; }
    __syncthreads();                                     // the ONLY barrier

    // ---- assemble per-thread exclusive prefixes ----
    float carryP_blk = 0.0f;
#pragma unroll
    for (int q = 0; q < WPB; ++q) carryP_blk += sRed[q];

    float cw = 0.0f, cp = 0.0f;                          // previous-wave carries
    for (int q = 0; q < w; ++q) { cw = fmaf(cw, f1024, LW[q]); cp += LP[q]; }

    float fw = 1.0f;                                     // f1024^w
    for (int q = 0; q < w; ++q) fw *= f1024;

    float fl = 1.0f, bse = f16;                          // f16^lane (square-multiply)
#pragma unroll
    for (int k = 0; k < 6; ++k) { if (lane & (1 << k)) fl *= bse; bse *= bse; }

    const float upW = __shfl_up(s, 1, 64);
    const float upP = __shfl_up(p, 1, 64);
    float Wcur = (lane ? upW : 0.0f) + fmaf(sCW, fw, cw) * fl;  // W at elem base
    float Pcur = (lane ? upP : 0.0f) + cp + carryP_blk;         // P at elem base

    // ---- emit 16 outputs/thread ----
    float af[9];
#pragma unroll
    for (int i = 0; i < 9; ++i) af[i] = ac[i];

    float4 o[4];
    float* oy = (float*)o;
#pragma unroll
    for (int i = 0; i < TPER; ++i) {
        const float x2 = fmaf(B1, Pcur, 1.0f);           // INITIAL_X2 = 1
        float poly = af[8];
#pragma unroll
        for (int j = 7; j >= 0; --j) poly = fmaf(poly, x2, af[j]);
        oy[i] = poly - B0 * Wcur - R0f * uu[i];
        Wcur = fmaf(A00, Wcur, uu[i]);                   // emit state BEFORE update
        Pcur += uu[i];
    }
    float4* op = (float4*)(out + base);
    op[0] = o[0]; op[1] = o[1]; op[2] = o[2]; op[3] = o[3];
}

extern "C" void kernel_launch(void* const* d_in, const int* in_sizes, int n_in,
                              void* d_out, int out_size, void* d_ws, size_t ws_size,
                              hipStream_t stream) {
    const float* u    = (const float*)d_in[0];
    const float* Rp_p = (const float*)d_in[1];
    const float* Cp_p = (const float*)d_in[2];
    const float* R0_p = (const float*)d_in[3];
    const float* ac   = (const float*)d_in[4];
    float* out = (float*)d_out;

    float* wsW = (float*)d_ws;        // [NB]
    float* wsP = (float*)d_ws + NB;   // [NB]

    kA_agg <<<NB, BLOCK, 0, stream>>>(u, Rp_p, Cp_p, wsW, wsP);
    kB_emit<<<NB, BLOCK, 0, stream>>>(u, Rp_p, Cp_p, R0_p, ac, wsW, wsP, out);
}